// Round 18
// baseline (128.144 us; speedup 1.0000x reference)
//
#include <hip/hip_runtime.h>
#include <hip/hip_bf16.h>

typedef __attribute__((ext_vector_type(4)))  float f32x4;
typedef __attribute__((ext_vector_type(16))) float f32x16;
typedef __bf16 bf16x8 __attribute__((ext_vector_type(8)));
typedef __attribute__((ext_vector_type(4))) unsigned int u32x4;
typedef __attribute__((ext_vector_type(4))) unsigned short u16x4;

#define MFMA16(a, b, c) __builtin_amdgcn_mfma_f32_16x16x32_bf16((a), (b), (c), 0, 0, 0)
#define MFMA32(a, b, c) __builtin_amdgcn_mfma_f32_32x32x16_bf16((a), (b), (c), 0, 0, 0)

#define LOG2E 1.4426950408889634f

#if __has_builtin(__builtin_amdgcn_exp2f)
#define EXP2(x) __builtin_amdgcn_exp2f(x)
#else
#define EXP2(x) exp2f(x)
#endif

static __device__ inline unsigned pk2(float a, float b) {
    unsigned short ua = __builtin_bit_cast(unsigned short, (__bf16)a);
    unsigned short ub = __builtin_bit_cast(unsigned short, (__bf16)b);
    return (unsigned)ua | ((unsigned)ub << 16);
}

// v_permlane32_swap_b32: x' = {x_low, y_low}, y' = {x_high, y_high}
static __device__ inline void plswap(unsigned& x, unsigned& y) {
#if __has_builtin(__builtin_amdgcn_permlane32_swap)
    auto r = __builtin_amdgcn_permlane32_swap((int)x, (int)y, false, false);
    x = (unsigned)r[0];
    y = (unsigned)r[1];
#else
    unsigned ox = (unsigned)__shfl_xor((int)x, 32);
    unsigned oy = (unsigned)__shfl_xor((int)y, 32);
    const bool lo = ((threadIdx.x & 63) < 32);
    unsigned nx = lo ? x : oy;
    unsigned ny = lo ? ox : y;
    x = nx; y = ny;
#endif
}

// async global -> LDS, 16B per lane. LDS dest: wave-uniform base + lane*16.
static __device__ inline void gll16(const void* g, void* l) {
    __builtin_amdgcn_global_load_lds(
        (const __attribute__((address_space(1))) void*)g,
        (__attribute__((address_space(3))) void*)l, 16, 0, 0);
}

// ---------------------------------------------------------------------------
// Kernel 0: fp32 -> bf16 convert. X (4Mi) -> Xb; Wq/Wk/Wv (1Mi each) -> Wb[3].
// ---------------------------------------------------------------------------
__global__ __launch_bounds__(256) void to_bf16(
    const float* __restrict__ X,
    const float* __restrict__ Wq, const float* __restrict__ Wk,
    const float* __restrict__ Wv,
    __bf16* __restrict__ Xb, __bf16* __restrict__ Wb)
{
    const size_t i = ((size_t)blockIdx.x * 256 + threadIdx.x) * 8;
    const size_t MI = (size_t)1 << 20;
    const float* src;
    __bf16* dst;
    size_t off;
    if (i < 4 * MI)      { src = X;  dst = Xb;          off = i; }
    else if (i < 5 * MI) { src = Wq; dst = Wb;          off = i - 4 * MI; }
    else if (i < 6 * MI) { src = Wk; dst = Wb + MI;     off = i - 5 * MI; }
    else                 { src = Wv; dst = Wb + 2 * MI; off = i - 6 * MI; }

    f32x4 a = *reinterpret_cast<const f32x4*>(src + off);
    f32x4 b = *reinterpret_cast<const f32x4*>(src + off + 4);
    bf16x8 o;
    #pragma unroll
    for (int j = 0; j < 4; ++j) { o[j] = (__bf16)a[j]; o[4 + j] = (__bf16)b[j]; }
    *reinterpret_cast<bf16x8*>(dst + off) = o;
}

// ---------------------------------------------------------------------------
// Kernel 1: QKV projection on bf16 inputs (R15 version, unchanged).
// z==2 writes V transposed via LDS one-shot epilogue.
// ---------------------------------------------------------------------------
__global__ __launch_bounds__(256) void qkv_gemm(
    const __bf16* __restrict__ Xb, const __bf16* __restrict__ Wb,
    const float* __restrict__ bq, const float* __restrict__ bk,
    const float* __restrict__ bv,
    __bf16* __restrict__ Qb, __bf16* __restrict__ Kb, __bf16* __restrict__ Vt)
{
    const int z = blockIdx.z;
    const __bf16* W   = Wb + (size_t)z * (1u << 20);
    const float* bias = (z == 0) ? bq : (z == 1) ? bk : bv;
    const float oscale = (z == 0) ? (0.125f * LOG2E) : 1.0f;

    const int row0 = blockIdx.x * 128;   // token dim (M)
    const int col0 = blockIdx.y * 128;   // e dim (N)

    __shared__ __align__(16) char SMEM[34816];
    char* As = SMEM;
    char* Bs = SMEM + 16384;

    const int t    = threadIdx.x;
    const int lane = t & 63;
    const int w    = t >> 6;
    const int wr   = w >> 1, wc = w & 1;
    const int l15  = lane & 15, g = lane >> 4;

    f32x4 zero = {0.f, 0.f, 0.f, 0.f};
    f32x4 acc[4][4];
    #pragma unroll
    for (int m = 0; m < 4; ++m)
        #pragma unroll
        for (int n = 0; n < 4; ++n) acc[m][n] = zero;

    const int srow  = t >> 3;
    const int sinner = 16 * ((t & 7) ^ ((t >> 3) & 7));
    const char* srcA[4];
    const char* srcB[4];
    #pragma unroll
    for (int i = 0; i < 4; ++i) {
        srcA[i] = (const char*)Xb + (size_t)(row0 + i * 32 + srow) * 2048 + sinner;
        srcB[i] = (const char*)W  + (size_t)(col0 + i * 32 + srow) * 2048 + sinner;
    }
    const int ldst = t * 16;

    for (int k0 = 0; k0 < 2048; k0 += 128) {
        __syncthreads();
        #pragma unroll
        for (int i = 0; i < 4; ++i) {
            gll16(srcA[i] + k0, As + i * 4096 + ldst);
            gll16(srcB[i] + k0, Bs + i * 4096 + ldst);
        }
        __syncthreads();

        #pragma unroll
        for (int ksub = 0; ksub < 2; ++ksub) {
            const int cb2 = ksub * 64 + g * 16;
            bf16x8 af[4], bw[4];
            #pragma unroll
            for (int m = 0; m < 4; ++m) {
                const int row = wr * 64 + m * 16 + l15;
                af[m] = *reinterpret_cast<const bf16x8*>(
                    As + row * 128 + (cb2 ^ ((row & 7) << 4)));
            }
            #pragma unroll
            for (int n = 0; n < 4; ++n) {
                const int row = wc * 64 + n * 16 + l15;
                bw[n] = *reinterpret_cast<const bf16x8*>(
                    Bs + row * 128 + (cb2 ^ ((row & 7) << 4)));
            }
            #pragma unroll
            for (int m = 0; m < 4; ++m)
                #pragma unroll
                for (int n = 0; n < 4; ++n)
                    acc[m][n] = MFMA16(af[m], bw[n], acc[m][n]);
        }
    }

    if (z == 2) {
        __syncthreads();
        #pragma unroll
        for (int n = 0; n < 4; ++n) {
            const int e = wc * 64 + n * 16 + l15;
            const float bv_ = bias[col0 + e];
            #pragma unroll
            for (int m = 0; m < 4; ++m) {
                const int tok = wr * 64 + m * 16 + g * 4;
                u16x4 pk;
                #pragma unroll
                for (int j = 0; j < 4; ++j)
                    pk[j] = __builtin_bit_cast(unsigned short,
                                               (__bf16)(acc[m][n][j] + bv_));
                *reinterpret_cast<u16x4*>(SMEM + e * 272 + tok * 2) = pk;
            }
        }
        __syncthreads();
        const int r = t >> 1, seg = t & 1;
        const int e = col0 + r;
        const int h = e >> 6, hd = e & 63;
        const int bb = row0 >> 11;
        const int s0 = (row0 & 2047) + seg * 64;
        __bf16* dst = Vt + (((size_t)((bb * 16 + h) * 64 + hd)) << 11) + s0;
        const char* srcT = SMEM + r * 272 + seg * 128;
        #pragma unroll
        for (int i = 0; i < 8; ++i)
            *reinterpret_cast<bf16x8*>(dst + i * 8) =
                *reinterpret_cast<const bf16x8*>(srcT + i * 16);
    } else {
        __bf16* Ob = (z == 0) ? Qb : Kb;
        #pragma unroll
        for (int n = 0; n < 4; ++n) {
            const int e  = col0 + wc * 64 + n * 16 + l15;
            const float bv_ = bias[e];
            const int h = e >> 6, hd = e & 63;
            #pragma unroll
            for (int m = 0; m < 4; ++m) {
                #pragma unroll
                for (int j = 0; j < 4; ++j) {
                    const int tok = row0 + wr * 64 + m * 16 + g * 4 + j;
                    const int b = tok >> 11, s = tok & 2047;
                    const int bh = b * 16 + h;
                    Ob[((size_t)(bh * 2048 + s) << 6) | hd] =
                        (__bf16)((acc[m][n][j] + bv_) * oscale);
                }
            }
        }
    }
}

// ---------------------------------------------------------------------------
// Kernel 2: flash attention, R18: FULLY DECOUPLED WAVES — zero main-loop
// barriers. Each wave (32 q rows, full 2048 KV) stages its OWN K tile into
// its OWN LDS region via gll16 (self-produced/self-consumed -> visibility by
// own-wave counted vmcnt(8), T4). V is read DIRECT from L2 (16B global
// loads issued at compute-top, consumed post-QK/exp; only 16 VGPR live).
// Static-max softmax; EXP2; mask as MFMA C-init. LDS 72KB -> 2 blocks/CU.
// ---------------------------------------------------------------------------
__global__ __launch_bounds__(256, 2) void flash_attn(
    const __bf16* __restrict__ Qb, const __bf16* __restrict__ Kb,
    const __bf16* __restrict__ Vt, const float* __restrict__ mask,
    float* __restrict__ out)
{
    // XCD swizzle: 512 blocks, 64/XCD -> 4 heads per XCD's L2 (2MB K+V)
    const int bid = blockIdx.x;       // 1-D grid of 512
    const int wid = (bid & 7) * 64 + (bid >> 3);
    const int qt  = wid & 15;         // q-tile of 128 rows (4 waves * 32)
    const int bh  = wid >> 4;
    const int b = bh >> 4, h = bh & 15;

    const int t = threadIdx.x;
    const int lane = t & 63;
    const int w = t >> 6;
    const int l31 = lane & 31, hi = lane >> 5;
    const int q = (qt * 4 + w) * 32 + l31;

    __shared__ __align__(16) char Ks[2][4][8192];   // [buf][wave][64 keys x 128B]
    __shared__ __align__(16) float mLs[2048];

    // ---- stage mask * log2e into LDS (one-time barrier below)
    {
        const float* mb = mask + b * 2048 + t * 8;
        f32x4 m0 = *reinterpret_cast<const f32x4*>(mb);
        f32x4 m1 = *reinterpret_cast<const f32x4*>(mb + 4);
        *reinterpret_cast<f32x4*>(&mLs[t * 8])     = m0 * LOG2E;
        *reinterpret_cast<f32x4*>(&mLs[t * 8 + 4]) = m1 * LOG2E;
    }

    // loop-invariant Q B-fragments
    bf16x8 qf[4];
    {
        const __bf16* qp = Qb + ((size_t)(bh * 2048 + q) << 6) + hi * 8;
        #pragma unroll
        for (int ds = 0; ds < 4; ++ds)
            qf[ds] = *reinterpret_cast<const bf16x8*>(qp + ds * 16);
    }

    f32x16 ctx0, ctx1;
    #pragma unroll
    for (int r = 0; r < 16; ++r) { ctx0[r] = 0.f; ctx1[r] = 0.f; }
    float lrow = 0.f;

    // ---- per-wave K staging precompute. Slot x in [0,8192): row = x>>7,
    // swz s(x)=((row&7)<<4); linear LDS dest + inverse-swizzled global src.
    const char* Kbase = (const char*)(Kb + ((size_t)bh << 17));
    const __bf16* Vbh = Vt + ((size_t)bh << 17);
    const char* srcK[8];
    int xslot[8];
    #pragma unroll
    for (int i = 0; i < 8; ++i) {
        const int x = i * 1024 + lane * 16;
        xslot[i] = x;
        srcK[i] = Kbase + (x ^ (((x >> 7) & 7) << 4));
    }

    auto stage = [&](int buf, int kt) {            // 8 gll16, own region only
        char* L = &Ks[buf][w][0];
        const size_t ko = (size_t)kt * 8192;
        #pragma unroll
        for (int i = 0; i < 8; ++i)
            gll16(srcK[i] + ko, L + xslot[i]);
    };

    const int swz = (l31 & 7) << 4;
    const int cb  = hi * 16;

    auto compute = [&](int buf, int kt) {
        const char* KB = &Ks[buf][w][0];
        const int kbase = kt * 64;

        // ---- V direct from L2: issued here, consumed after QK/exp shadow
        const __bf16* vp0 = Vbh + ((size_t)l31 << 11) + kbase;
        const __bf16* vp1 = Vbh + ((size_t)(32 + l31) << 11) + kbase;
        bf16x8 vv[8];
        #pragma unroll
        for (int ks = 0; ks < 4; ++ks) {
            vv[ks]     = *reinterpret_cast<const bf16x8*>(vp0 + ks * 16 + hi * 8);
            vv[4 + ks] = *reinterpret_cast<const bf16x8*>(vp1 + ks * 16 + hi * 8);
        }

        // ---- K fragments from own LDS (swizzled ds_read_b128)
        bf16x8 kc[8];
        #pragma unroll
        for (int ds = 0; ds < 4; ++ds) {
            const int c = (ds * 32 + cb) ^ swz;
            kc[ds]     = *reinterpret_cast<const bf16x8*>(KB + l31 * 128 + c);
            kc[4 + ds] = *reinterpret_cast<const bf16x8*>(KB + (32 + l31) * 128 + c);
        }

        // ---- scores init = mask (log2 domain); reg r=4c+j -> k = j+8c+4hi
        f32x16 pt0, pt1;
        #pragma unroll
        for (int c = 0; c < 4; ++c) {
            f32x4 mv0 = *reinterpret_cast<const f32x4*>(&mLs[kbase + 4 * hi + 8 * c]);
            f32x4 mv1 = *reinterpret_cast<const f32x4*>(&mLs[kbase + 32 + 4 * hi + 8 * c]);
            #pragma unroll
            for (int j = 0; j < 4; ++j) { pt0[4 * c + j] = mv0[j]; pt1[4 * c + j] = mv1[j]; }
        }

        // ---- QK^T
        __builtin_amdgcn_s_setprio(1);
        #pragma unroll
        for (int ds = 0; ds < 4; ++ds) {
            pt0 = MFMA32(kc[ds],     qf[ds], pt0);
            pt1 = MFMA32(kc[4 + ds], qf[ds], pt1);
        }
        __builtin_amdgcn_s_setprio(0);

        // ---- static-max softmax: P = exp2(S)
        float ps = 0.f;
        #pragma unroll
        for (int r = 0; r < 16; ++r) {
            float e = EXP2(pt0[r]);
            pt0[r] = e; ps += e;
        }
        #pragma unroll
        for (int r = 0; r < 16; ++r) {
            float e = EXP2(pt1[r]);
            pt1[r] = e; ps += e;
        }
        ps += __shfl_xor(ps, 32);
        lrow += ps;

        // ---- P^T -> PV B-operand (16 packs + 8 permlane32_swap), then PV
        __builtin_amdgcn_s_setprio(1);
        #pragma unroll
        for (int ks = 0; ks < 4; ++ks) {
            const f32x16& P = (ks < 2) ? pt0 : pt1;
            const int base = 8 * (ks & 1);
            unsigned a0 = pk2(P[base + 0], P[base + 1]);
            unsigned b0 = pk2(P[base + 4], P[base + 5]);
            unsigned a1 = pk2(P[base + 2], P[base + 3]);
            unsigned b1 = pk2(P[base + 6], P[base + 7]);
            plswap(a0, b0);
            plswap(a1, b1);
            u32x4 wv = {a0, a1, b0, b1};
            bf16x8 pb = __builtin_bit_cast(bf16x8, wv);
            ctx0 = MFMA32(vv[ks],     pb, ctx0);
            ctx1 = MFMA32(vv[4 + ks], pb, ctx1);
        }
        __builtin_amdgcn_s_setprio(0);
    };

    // ---- prologue: stage K(0); one block barrier (mask visibility only)
    stage(0, 0);
    __syncthreads();

    // ---- barrier-free main loop: stage(kt+1) 1-ahead; own-wave counted
    // vmcnt(8) = K(kt)'s 8 loads complete, K(kt+1)'s 8 stay in flight.
    for (int kt = 0; kt < 32; ++kt) {
        const int nk = (kt + 1 < 32) ? kt + 1 : 31;   // tail: redundant restage
        stage((kt + 1) & 1, nk);
        asm volatile("s_waitcnt vmcnt(8)" ::: "memory");
        __builtin_amdgcn_sched_barrier(0);
        compute(kt & 1, kt);
    }

    // ---- epilogue: ctx^T C-layout -> out fp32 [b][s][h*64 + d]
    const float inv = 1.0f / lrow;
    float* op = out + (((size_t)(b * 2048 + q)) << 10) + h * 64;
    #pragma unroll
    for (int c = 0; c < 4; ++c) {
        f32x4 s0v = {ctx0[4 * c + 0] * inv, ctx0[4 * c + 1] * inv,
                     ctx0[4 * c + 2] * inv, ctx0[4 * c + 3] * inv};
        f32x4 s1v = {ctx1[4 * c + 0] * inv, ctx1[4 * c + 1] * inv,
                     ctx1[4 * c + 2] * inv, ctx1[4 * c + 3] * inv};
        *reinterpret_cast<f32x4*>(op + 8 * c + 4 * hi)      = s0v;
        *reinterpret_cast<f32x4*>(op + 32 + 8 * c + 4 * hi) = s1v;
    }
}

// ---------------------------------------------------------------------------
extern "C" void kernel_launch(void* const* d_in, const int* in_sizes, int n_in,
                              void* d_out, int out_size, void* d_ws, size_t ws_size,
                              hipStream_t stream)
{
    const float* X    = (const float*)d_in[0];
    const float* mask = (const float*)d_in[1];
    const float* Wq   = (const float*)d_in[2];
    const float* bq   = (const float*)d_in[3];
    const float* Wk   = (const float*)d_in[4];
    const float* bk   = (const float*)d_in[5];
    const float* Wv   = (const float*)d_in[6];
    const float* bv   = (const float*)d_in[7];
    float* out = (float*)d_out;

    // ws layout (bf16 elems): Qb[4Mi] Kb[4Mi] Vt[4Mi] Xb[4Mi] Wb[3Mi] = 38MB
    const size_t MI = (size_t)1 << 20;
    __bf16* Qb = (__bf16*)d_ws;
    __bf16* Kb = Qb + 4 * MI;
    __bf16* Vt = Kb + 4 * MI;
    __bf16* Xb = Vt + 4 * MI;
    __bf16* Wb = Xb + 4 * MI;

    to_bf16<<<dim3(3584), 256, 0, stream>>>(X, Wq, Wk, Wv, Xb, Wb);
    qkv_gemm<<<dim3(32, 8, 3), 256, 0, stream>>>(Xb, Wb, bq, bk, bv, Qb, Kb, Vt);
    flash_attn<<<dim3(512), 256, 0, stream>>>(Qb, Kb, Vt, mask, out);
}

// Round 19
// 96.849 us; speedup vs baseline: 1.3231x; 1.3231x over previous
//
#include <hip/hip_runtime.h>
#include <hip/hip_bf16.h>

typedef __attribute__((ext_vector_type(4)))  float f32x4;
typedef __attribute__((ext_vector_type(16))) float f32x16;
typedef __bf16 bf16x8 __attribute__((ext_vector_type(8)));
typedef __attribute__((ext_vector_type(4))) unsigned int u32x4;
typedef __attribute__((ext_vector_type(4))) unsigned short u16x4;

#define MFMA16(a, b, c) __builtin_amdgcn_mfma_f32_16x16x32_bf16((a), (b), (c), 0, 0, 0)
#define MFMA32(a, b, c) __builtin_amdgcn_mfma_f32_32x32x16_bf16((a), (b), (c), 0, 0, 0)

#define LOG2E 1.4426950408889634f

#if __has_builtin(__builtin_amdgcn_exp2f)
#define EXP2(x) __builtin_amdgcn_exp2f(x)
#else
#define EXP2(x) exp2f(x)
#endif

static __device__ inline unsigned pk2(float a, float b) {
    unsigned short ua = __builtin_bit_cast(unsigned short, (__bf16)a);
    unsigned short ub = __builtin_bit_cast(unsigned short, (__bf16)b);
    return (unsigned)ua | ((unsigned)ub << 16);
}

// v_permlane32_swap_b32: x' = {x_low, y_low}, y' = {x_high, y_high}
static __device__ inline void plswap(unsigned& x, unsigned& y) {
#if __has_builtin(__builtin_amdgcn_permlane32_swap)
    auto r = __builtin_amdgcn_permlane32_swap((int)x, (int)y, false, false);
    x = (unsigned)r[0];
    y = (unsigned)r[1];
#else
    unsigned ox = (unsigned)__shfl_xor((int)x, 32);
    unsigned oy = (unsigned)__shfl_xor((int)y, 32);
    const bool lo = ((threadIdx.x & 63) < 32);
    unsigned nx = lo ? x : oy;
    unsigned ny = lo ? ox : y;
    x = nx; y = ny;
#endif
}

// async global -> LDS, 16B per lane. LDS dest: wave-uniform base + lane*16.
static __device__ inline void gll16(const void* g, void* l) {
    __builtin_amdgcn_global_load_lds(
        (const __attribute__((address_space(1))) void*)g,
        (__attribute__((address_space(3))) void*)l, 16, 0, 0);
}

// ---------------------------------------------------------------------------
// Kernel 0: fp32 -> bf16 convert. X (4Mi) -> Xb; Wq/Wk/Wv (1Mi each) -> Wb[3].
// ---------------------------------------------------------------------------
__global__ __launch_bounds__(256) void to_bf16(
    const float* __restrict__ X,
    const float* __restrict__ Wq, const float* __restrict__ Wk,
    const float* __restrict__ Wv,
    __bf16* __restrict__ Xb, __bf16* __restrict__ Wb)
{
    const size_t i = ((size_t)blockIdx.x * 256 + threadIdx.x) * 8;
    const size_t MI = (size_t)1 << 20;
    const float* src;
    __bf16* dst;
    size_t off;
    if (i < 4 * MI)      { src = X;  dst = Xb;          off = i; }
    else if (i < 5 * MI) { src = Wq; dst = Wb;          off = i - 4 * MI; }
    else if (i < 6 * MI) { src = Wk; dst = Wb + MI;     off = i - 5 * MI; }
    else                 { src = Wv; dst = Wb + 2 * MI; off = i - 6 * MI; }

    f32x4 a = *reinterpret_cast<const f32x4*>(src + off);
    f32x4 b = *reinterpret_cast<const f32x4*>(src + off + 4);
    bf16x8 o;
    #pragma unroll
    for (int j = 0; j < 4; ++j) { o[j] = (__bf16)a[j]; o[4 + j] = (__bf16)b[j]; }
    *reinterpret_cast<bf16x8*>(dst + off) = o;
}

// ---------------------------------------------------------------------------
// Kernel 1: QKV projection on bf16 inputs (R15 version).
// z==2 writes V transposed via LDS one-shot epilogue.
// ---------------------------------------------------------------------------
__global__ __launch_bounds__(256) void qkv_gemm(
    const __bf16* __restrict__ Xb, const __bf16* __restrict__ Wb,
    const float* __restrict__ bq, const float* __restrict__ bk,
    const float* __restrict__ bv,
    __bf16* __restrict__ Qb, __bf16* __restrict__ Kb, __bf16* __restrict__ Vt)
{
    const int z = blockIdx.z;
    const __bf16* W   = Wb + (size_t)z * (1u << 20);
    const float* bias = (z == 0) ? bq : (z == 1) ? bk : bv;
    const float oscale = (z == 0) ? (0.125f * LOG2E) : 1.0f;

    const int row0 = blockIdx.x * 128;   // token dim (M)
    const int col0 = blockIdx.y * 128;   // e dim (N)

    __shared__ __align__(16) char SMEM[34816];
    char* As = SMEM;
    char* Bs = SMEM + 16384;

    const int t    = threadIdx.x;
    const int lane = t & 63;
    const int w    = t >> 6;
    const int wr   = w >> 1, wc = w & 1;
    const int l15  = lane & 15, g = lane >> 4;

    f32x4 zero = {0.f, 0.f, 0.f, 0.f};
    f32x4 acc[4][4];
    #pragma unroll
    for (int m = 0; m < 4; ++m)
        #pragma unroll
        for (int n = 0; n < 4; ++n) acc[m][n] = zero;

    const int srow  = t >> 3;
    const int sinner = 16 * ((t & 7) ^ ((t >> 3) & 7));
    const char* srcA[4];
    const char* srcB[4];
    #pragma unroll
    for (int i = 0; i < 4; ++i) {
        srcA[i] = (const char*)Xb + (size_t)(row0 + i * 32 + srow) * 2048 + sinner;
        srcB[i] = (const char*)W  + (size_t)(col0 + i * 32 + srow) * 2048 + sinner;
    }
    const int ldst = t * 16;

    for (int k0 = 0; k0 < 2048; k0 += 128) {
        __syncthreads();
        #pragma unroll
        for (int i = 0; i < 4; ++i) {
            gll16(srcA[i] + k0, As + i * 4096 + ldst);
            gll16(srcB[i] + k0, Bs + i * 4096 + ldst);
        }
        __syncthreads();

        #pragma unroll
        for (int ksub = 0; ksub < 2; ++ksub) {
            const int cb2 = ksub * 64 + g * 16;
            bf16x8 af[4], bw[4];
            #pragma unroll
            for (int m = 0; m < 4; ++m) {
                const int row = wr * 64 + m * 16 + l15;
                af[m] = *reinterpret_cast<const bf16x8*>(
                    As + row * 128 + (cb2 ^ ((row & 7) << 4)));
            }
            #pragma unroll
            for (int n = 0; n < 4; ++n) {
                const int row = wc * 64 + n * 16 + l15;
                bw[n] = *reinterpret_cast<const bf16x8*>(
                    Bs + row * 128 + (cb2 ^ ((row & 7) << 4)));
            }
            #pragma unroll
            for (int m = 0; m < 4; ++m)
                #pragma unroll
                for (int n = 0; n < 4; ++n)
                    acc[m][n] = MFMA16(af[m], bw[n], acc[m][n]);
        }
    }

    if (z == 2) {
        __syncthreads();
        #pragma unroll
        for (int n = 0; n < 4; ++n) {
            const int e = wc * 64 + n * 16 + l15;
            const float bv_ = bias[col0 + e];
            #pragma unroll
            for (int m = 0; m < 4; ++m) {
                const int tok = wr * 64 + m * 16 + g * 4;
                u16x4 pk;
                #pragma unroll
                for (int j = 0; j < 4; ++j)
                    pk[j] = __builtin_bit_cast(unsigned short,
                                               (__bf16)(acc[m][n][j] + bv_));
                *reinterpret_cast<u16x4*>(SMEM + e * 272 + tok * 2) = pk;
            }
        }
        __syncthreads();
        const int r = t >> 1, seg = t & 1;
        const int e = col0 + r;
        const int h = e >> 6, hd = e & 63;
        const int bb = row0 >> 11;
        const int s0 = (row0 & 2047) + seg * 64;
        __bf16* dst = Vt + (((size_t)((bb * 16 + h) * 64 + hd)) << 11) + s0;
        const char* srcT = SMEM + r * 272 + seg * 128;
        #pragma unroll
        for (int i = 0; i < 8; ++i)
            *reinterpret_cast<bf16x8*>(dst + i * 8) =
                *reinterpret_cast<const bf16x8*>(srcT + i * 16);
    } else {
        __bf16* Ob = (z == 0) ? Qb : Kb;
        #pragma unroll
        for (int n = 0; n < 4; ++n) {
            const int e  = col0 + wc * 64 + n * 16 + l15;
            const float bv_ = bias[e];
            const int h = e >> 6, hd = e & 63;
            #pragma unroll
            for (int m = 0; m < 4; ++m) {
                #pragma unroll
                for (int j = 0; j < 4; ++j) {
                    const int tok = row0 + wr * 64 + m * 16 + g * 4 + j;
                    const int b = tok >> 11, s = tok & 2047;
                    const int bh = b * 16 + h;
                    Ob[((size_t)(bh * 2048 + s) << 6) | hd] =
                        (__bf16)((acc[m][n][j] + bv_) * oscale);
                }
            }
        }
    }
}

// ---------------------------------------------------------------------------
// Kernel 2: flash attention, R16 structure (best measured): wave = 64 q x
// 1024 keys; (qsub, kvh) waves; kc/vv shared by two q-sub-blocks; static-max
// softmax; EXP2; gll16 LDS double-buffer + XOR swizzle; pure-add combine.
// ---------------------------------------------------------------------------
__global__ __launch_bounds__(256, 2) void flash_attn(
    const __bf16* __restrict__ Qb, const __bf16* __restrict__ Kb,
    const __bf16* __restrict__ Vt, const float* __restrict__ mask,
    float* __restrict__ out)
{
    // XCD swizzle: 512 blocks, 64/XCD -> 4 heads per XCD's L2 (2MB K+V)
    const int bid = blockIdx.x;       // 1-D grid of 512
    const int wid = (bid & 7) * 64 + (bid >> 3);
    const int qt  = wid & 15;         // q-tile of 128 rows
    const int bh  = wid >> 4;
    const int b = bh >> 4, h = bh & 15;

    const int t = threadIdx.x;
    const int lane = t & 63;
    const int w = t >> 6;             // 0..3
    const int qsub = w >> 1;          // q sub-tile (64 rows each)
    const int kvh  = w & 1;           // KV half: 0 -> [0,1024), 1 -> [1024,2048)
    const int l31 = lane & 31, hi = lane >> 5;
    const int qA = qt * 128 + qsub * 64 + l31;    // q-block A row (B = +32)

    __shared__ __align__(16) char KV[2][2][16384];  // [buf][kvh][K 8KB | V 8KB]
    __shared__ __align__(16) float mLs[2048];
    __shared__ float lSa[2][64], lSb[2][64];

    // ---- stage mask * log2e into LDS
    {
        const float* mb = mask + b * 2048 + t * 8;
        f32x4 m0 = *reinterpret_cast<const f32x4*>(mb);
        f32x4 m1 = *reinterpret_cast<const f32x4*>(mb + 4);
        *reinterpret_cast<f32x4*>(&mLs[t * 8])     = m0 * LOG2E;
        *reinterpret_cast<f32x4*>(&mLs[t * 8 + 4]) = m1 * LOG2E;
    }

    // loop-invariant Q B-fragments for both q-blocks
    bf16x8 qfA[4], qfB[4];
    {
        const __bf16* qp = Qb + ((size_t)(bh * 2048 + qA) << 6) + hi * 8;
        #pragma unroll
        for (int ds = 0; ds < 4; ++ds) {
            qfA[ds] = *reinterpret_cast<const bf16x8*>(qp + ds * 16);
            qfB[ds] = *reinterpret_cast<const bf16x8*>(qp + 2048 + ds * 16);  // +32 rows
        }
    }

    f32x16 cA0, cA1, cB0, cB1;
    #pragma unroll
    for (int r = 0; r < 16; ++r) { cA0[r] = 0.f; cA1[r] = 0.f; cB0[r] = 0.f; cB1[r] = 0.f; }
    float lrowA = 0.f, lrowB = 0.f;

    // ---- staging precompute. Stream kvh: 8KB K-tile + 8KB V-tile per step,
    // filled by this stream's 2 waves (qsub regions). slot x: row=x>>7,
    // s(x)=((row&7)<<4); linear LDS dest + inverse-swizzled global src.
    const char* KbaseH = (const char*)(Kb + ((size_t)bh << 17))
                       + (size_t)kvh * 131072;     // +1024 keys * 128B
    const char* VbaseH = (const char*)(Vt + ((size_t)bh << 17))
                       + (size_t)kvh * 2048;       // +1024 cols * 2B
    const char* srcK[4];
    const char* srcV[4];
    int xslot[4];
    #pragma unroll
    for (int i = 0; i < 4; ++i) {
        const int x = qsub * 1024 + i * 2048 + lane * 16;
        xslot[i] = x;
        srcK[i] = KbaseH + (x ^ (((x >> 7) & 7) << 4));
        srcV[i] = VbaseH + (size_t)(x >> 7) * 4096
                         + ((x & 127) ^ (((x >> 7) & 7) << 4));
    }

    auto stage = [&](int buf, int kt) {
        char* L = &KV[buf][kvh][0];
        const size_t ko = (size_t)kt * 8192;   // 64 keys * 128B
        const size_t vo = (size_t)kt * 128;    // 64 cols * 2B
        #pragma unroll
        for (int i = 0; i < 4; ++i) {
            gll16(srcK[i] + ko, L + xslot[i]);
            gll16(srcV[i] + vo, L + 8192 + xslot[i]);
        }
    };

    const int swz = (l31 & 7) << 4;
    const int cb  = hi * 16;

    auto compute = [&](int buf, int kt) {
        const char* KB = &KV[buf][kvh][0];
        const int kbase = kvh * 1024 + kt * 64;    // mask index base

        // ---- K fragments (swizzled ds_read_b128), shared by A and B
        bf16x8 kc[8];
        #pragma unroll
        for (int ds = 0; ds < 4; ++ds) {
            const int c = (ds * 32 + cb) ^ swz;
            kc[ds]     = *reinterpret_cast<const bf16x8*>(KB + l31 * 128 + c);
            kc[4 + ds] = *reinterpret_cast<const bf16x8*>(KB + (32 + l31) * 128 + c);
        }

        // ---- scores init = mask (log2 domain), shared by A and B
        f32x16 pA0, pA1, pB0, pB1;
        #pragma unroll
        for (int c = 0; c < 4; ++c) {
            f32x4 mv0 = *reinterpret_cast<const f32x4*>(&mLs[kbase + 4 * hi + 8 * c]);
            f32x4 mv1 = *reinterpret_cast<const f32x4*>(&mLs[kbase + 32 + 4 * hi + 8 * c]);
            #pragma unroll
            for (int j = 0; j < 4; ++j) {
                pA0[4 * c + j] = mv0[j];  pA1[4 * c + j] = mv1[j];
                pB0[4 * c + j] = mv0[j];  pB1[4 * c + j] = mv1[j];
            }
        }

        // ---- QK^T for both q-blocks (kc shared)
        __builtin_amdgcn_s_setprio(1);
        #pragma unroll
        for (int ds = 0; ds < 4; ++ds) {
            pA0 = MFMA32(kc[ds],     qfA[ds], pA0);
            pA1 = MFMA32(kc[4 + ds], qfA[ds], pA1);
            pB0 = MFMA32(kc[ds],     qfB[ds], pB0);
            pB1 = MFMA32(kc[4 + ds], qfB[ds], pB1);
        }
        __builtin_amdgcn_s_setprio(0);

        // ---- static-max softmax, two streams
        float psA = 0.f, psB = 0.f;
        #pragma unroll
        for (int r = 0; r < 16; ++r) {
            float eA0 = EXP2(pA0[r]);  pA0[r] = eA0;  psA += eA0;
            float eB0 = EXP2(pB0[r]);  pB0[r] = eB0;  psB += eB0;
        }
        #pragma unroll
        for (int r = 0; r < 16; ++r) {
            float eA1 = EXP2(pA1[r]);  pA1[r] = eA1;  psA += eA1;
            float eB1 = EXP2(pB1[r]);  pB1[r] = eB1;  psB += eB1;
        }
        psA += __shfl_xor(psA, 32);
        psB += __shfl_xor(psB, 32);
        lrowA += psA;  lrowB += psB;

        // ---- PV: vv shared by A and B; pack per ks to cap VGPR
        const char* VB = KB + 8192;
        __builtin_amdgcn_s_setprio(1);
        #pragma unroll
        for (int ks = 0; ks < 4; ++ks) {
            const int c = (ks * 32 + cb) ^ swz;
            bf16x8 vv0 = *reinterpret_cast<const bf16x8*>(VB + l31 * 128 + c);
            bf16x8 vv1 = *reinterpret_cast<const bf16x8*>(VB + (32 + l31) * 128 + c);

            const f32x16& PA = (ks < 2) ? pA0 : pA1;
            const f32x16& PB = (ks < 2) ? pB0 : pB1;
            const int base = 8 * (ks & 1);
            unsigned a0 = pk2(PA[base + 0], PA[base + 1]);
            unsigned b0 = pk2(PA[base + 4], PA[base + 5]);
            unsigned a1 = pk2(PA[base + 2], PA[base + 3]);
            unsigned b1 = pk2(PA[base + 6], PA[base + 7]);
            plswap(a0, b0);
            plswap(a1, b1);
            u32x4 wvA = {a0, a1, b0, b1};
            bf16x8 pbA = __builtin_bit_cast(bf16x8, wvA);
            cA0 = MFMA32(vv0, pbA, cA0);
            cA1 = MFMA32(vv1, pbA, cA1);

            unsigned c0 = pk2(PB[base + 0], PB[base + 1]);
            unsigned d0 = pk2(PB[base + 4], PB[base + 5]);
            unsigned c1 = pk2(PB[base + 2], PB[base + 3]);
            unsigned d1 = pk2(PB[base + 6], PB[base + 7]);
            plswap(c0, d0);
            plswap(c1, d1);
            u32x4 wvB = {c0, c1, d0, d1};
            bf16x8 pbB = __builtin_bit_cast(bf16x8, wvB);
            cB0 = MFMA32(vv0, pbB, cB0);
            cB1 = MFMA32(vv1, pbB, cB1);
        }
        __builtin_amdgcn_s_setprio(0);
    };

    // ---- 2-phase pipelined main loop over this stream's 16 tiles
    stage(0, 0);
    __syncthreads();
    for (int kt = 0; kt < 16; kt += 2) {
        stage(1, kt + 1);
        compute(0, kt);
        __syncthreads();
        if (kt + 2 < 16) stage(0, kt + 2);
        compute(1, kt + 1);
        __syncthreads();
    }

    // ================= KV-half combine (pure add; static-max) =================
    // kvh=1 waves publish ctx + lrow through LDS (KV scratch is dead now).
    char* cb_ = &KV[0][0][0] + qsub * 17408 + (size_t)lane * 272;
    if (kvh) {
        #pragma unroll
        for (int c = 0; c < 4; ++c) {
            *reinterpret_cast<f32x4*>(cb_ + c * 16) =
                f32x4{cA0[4*c+0], cA0[4*c+1], cA0[4*c+2], cA0[4*c+3]};
            *reinterpret_cast<f32x4*>(cb_ + 64 + c * 16) =
                f32x4{cA1[4*c+0], cA1[4*c+1], cA1[4*c+2], cA1[4*c+3]};
            *reinterpret_cast<f32x4*>(cb_ + 128 + c * 16) =
                f32x4{cB0[4*c+0], cB0[4*c+1], cB0[4*c+2], cB0[4*c+3]};
            *reinterpret_cast<f32x4*>(cb_ + 192 + c * 16) =
                f32x4{cB1[4*c+0], cB1[4*c+1], cB1[4*c+2], cB1[4*c+3]};
        }
        lSa[qsub][lane] = lrowA;
        lSb[qsub][lane] = lrowB;
    }
    __syncthreads();
    if (!kvh) {
        #pragma unroll
        for (int c = 0; c < 4; ++c) {
            f32x4 pa0 = *reinterpret_cast<const f32x4*>(cb_ + c * 16);
            f32x4 pa1 = *reinterpret_cast<const f32x4*>(cb_ + 64 + c * 16);
            f32x4 pb0 = *reinterpret_cast<const f32x4*>(cb_ + 128 + c * 16);
            f32x4 pb1 = *reinterpret_cast<const f32x4*>(cb_ + 192 + c * 16);
            #pragma unroll
            for (int j = 0; j < 4; ++j) {
                cA0[4*c+j] += pa0[j];  cA1[4*c+j] += pa1[j];
                cB0[4*c+j] += pb0[j];  cB1[4*c+j] += pb1[j];
            }
        }
        const float invA = 1.0f / (lrowA + lSa[qsub][lane]);
        const float invB = 1.0f / (lrowB + lSb[qsub][lane]);

        float* opA = out + (((size_t)(b * 2048 + qA)) << 10) + h * 64;
        float* opB = opA + ((size_t)32 << 10);   // +32 rows
        #pragma unroll
        for (int c = 0; c < 4; ++c) {
            f32x4 s0v = {cA0[4*c+0] * invA, cA0[4*c+1] * invA,
                         cA0[4*c+2] * invA, cA0[4*c+3] * invA};
            f32x4 s1v = {cA1[4*c+0] * invA, cA1[4*c+1] * invA,
                         cA1[4*c+2] * invA, cA1[4*c+3] * invA};
            *reinterpret_cast<f32x4*>(opA + 8 * c + 4 * hi)      = s0v;
            *reinterpret_cast<f32x4*>(opA + 32 + 8 * c + 4 * hi) = s1v;
            f32x4 t0v = {cB0[4*c+0] * invB, cB0[4*c+1] * invB,
                         cB0[4*c+2] * invB, cB0[4*c+3] * invB};
            f32x4 t1v = {cB1[4*c+0] * invB, cB1[4*c+1] * invB,
                         cB1[4*c+2] * invB, cB1[4*c+3] * invB};
            *reinterpret_cast<f32x4*>(opB + 8 * c + 4 * hi)      = t0v;
            *reinterpret_cast<f32x4*>(opB + 32 + 8 * c + 4 * hi) = t1v;
        }
    }
}

// ---------------------------------------------------------------------------
extern "C" void kernel_launch(void* const* d_in, const int* in_sizes, int n_in,
                              void* d_out, int out_size, void* d_ws, size_t ws_size,
                              hipStream_t stream)
{
    const float* X    = (const float*)d_in[0];
    const float* mask = (const float*)d_in[1];
    const float* Wq   = (const float*)d_in[2];
    const float* bq   = (const float*)d_in[3];
    const float* Wk   = (const float*)d_in[4];
    const float* bk   = (const float*)d_in[5];
    const float* Wv   = (const float*)d_in[6];
    const float* bv   = (const float*)d_in[7];
    float* out = (float*)d_out;

    // ws layout (bf16 elems): Qb[4Mi] Kb[4Mi] Vt[4Mi] Xb[4Mi] Wb[3Mi] = 38MB
    const size_t MI = (size_t)1 << 20;
    __bf16* Qb = (__bf16*)d_ws;
    __bf16* Kb = Qb + 4 * MI;
    __bf16* Vt = Kb + 4 * MI;
    __bf16* Xb = Vt + 4 * MI;
    __bf16* Wb = Xb + 4 * MI;

    to_bf16<<<dim3(3584), 256, 0, stream>>>(X, Wq, Wk, Wv, Xb, Wb);
    qkv_gemm<<<dim3(32, 8, 3), 256, 0, stream>>>(Xb, Wb, bq, bk, bv, Qb, Kb, Vt);
    flash_attn<<<dim3(512), 256, 0, stream>>>(Qb, Kb, Vt, mask, out);
}